// Round 1
// 279.880 us; speedup vs baseline: 1.0383x; 1.0383x over previous
//
#include <hip/hip_runtime.h>

// DIN attention unit, MI355X — round 7: kill the latency stalls.
// R6 diagnosis: all passes issue-stalled (VALUBusy 19%, HBM 8%, occ 16%).
//  (1) pass1 rebuilt pass2-style: exclusive row ownership (no 4x redundant
//      loads), 8 positions/thread, all 32 channels/thread -> 2700cy of FMA
//      per row-load batch, latency self-hiding.
//  (2) weights moved OFF the LDS pipe: read as wave-uniform global loads
//      (compiler scalarizes to s_load via constant cache); VALU consumes
//      them as the free SGPR operand of v_fmac. Main loops use ZERO LDS.
//  (3) atomic fan-in split across 8 slots, summed in finalize.
// mask input UNUSED (reference uses unmasked scores — reproduced bug).

#define BB 512
#define TT 2048
#define DD 20
#define C0 32
#define C1 16

#define NTH 256            // 4 waves/block
#define NPOS 4             // positions per register round
#define POSB (NTH * NPOS)  // 1024 positions per chunk
#define NSLOT 8            // atomic slot-split

// ws float offsets
#define WS_P1 0                     // 8 slots * (32 sum + 32 sq)
#define WS_P2 512                   // 8 slots * (16 sum + 16 sq)
#define WS_SCALE0 768
#define WS_SHIFT0 800
#define WS_SCALE1 832
#define WS_SHIFT1 848
#define WS_ZERO_N 768               // floats to zero each launch
#define WS_BLOB 896
#define BLOB_J 24                   // 20 wM + c + pad
#define BLOB_B (C0 * BLOB_J)        // 768 floats per batch

#define PIN(x) asm volatile("" : "+v"(x))

__device__ __forceinline__ float fast_sigmoid(float x) {
    return __builtin_amdgcn_rcpf(1.0f + __expf(-x));
}

__device__ __forceinline__ void load_krow(const float* __restrict__ row,
                                          float* kk) {
    const float4* kr = (const float4*)row;  // rows are 80B => 16B aligned
    float4 a = kr[0], b = kr[1], c = kr[2], d = kr[3], e = kr[4];
    kk[0] = a.x; kk[1] = a.y; kk[2] = a.z; kk[3] = a.w;
    kk[4] = b.x; kk[5] = b.y; kk[6] = b.z; kk[7] = b.w;
    kk[8] = c.x; kk[9] = c.y; kk[10] = c.z; kk[11] = c.w;
    kk[12] = d.x; kk[13] = d.y; kk[14] = d.z; kk[15] = d.w;
    kk[16] = e.x; kk[17] = e.y; kk[18] = e.z; kk[19] = e.w;
}

// ---------------- prep: fold query into layer-1 weights ----------------
__global__ void prep_kernel(const float* __restrict__ query,
                            const float* __restrict__ W0,
                            const float* __restrict__ b0,
                            float* __restrict__ blob) {
    const int b = blockIdx.x * 2 + (threadIdx.x >> 5);
    const int j = threadIdx.x & 31;
    float cj = b0[j];
    float* dst = blob + (size_t)b * BLOB_B + j * BLOB_J;
#pragma unroll
    for (int d = 0; d < DD; ++d) {
        float w_q = W0[d * C0 + j];
        float w_k = W0[(DD + d) * C0 + j];
        float w_d = W0[(2 * DD + d) * C0 + j];
        float w_p = W0[(3 * DD + d) * C0 + j];
        float qd = query[b * DD + d];
        dst[d] = w_k - w_d + qd * w_p;
        cj = fmaf(qd, w_q + w_d, cj);
    }
    dst[20] = cj;
}

// ---------------- pass 1: layer-1 pre-activation stats ----------------
// One block per batch (512 blocks). Each thread owns 8 positions (2 rounds
// of 4 register-resident rows), computes all 32 channels, accumulates
// s[32]/q[32] in registers (fully static indexing), one wave butterfly at
// the end, slot-split atomic fan-in.
__global__ __launch_bounds__(NTH, 2) void pass1_kernel(
    const float* __restrict__ keys, const float* __restrict__ blob,
    float* __restrict__ sums) {
    const int b = blockIdx.x;
    const int tid = threadIdx.x, lane = tid & 63;
    const float* bA = blob + (size_t)b * BLOB_B;
    const float* kbase = keys + (size_t)b * TT * DD;

    float s[C0], q[C0];
#pragma unroll
    for (int j = 0; j < C0; ++j) { s[j] = 0.f; q[j] = 0.f; }

#pragma unroll 1
    for (int r = 0; r < TT / POSB; ++r) {
        float kk[NPOS][DD];
#pragma unroll
        for (int pp = 0; pp < NPOS; ++pp)
            load_krow(kbase + (size_t)(r * POSB + tid + pp * NTH) * DD,
                      kk[pp]);
#pragma unroll
        for (int pp = 0; pp < NPOS; ++pp)
#pragma unroll
            for (int d = 0; d < DD; ++d) PIN(kk[pp][d]);
#pragma unroll
        for (int j = 0; j < C0; ++j) {
            const float* wr = bA + j * BLOB_J;  // uniform -> s_load
            const float cj = wr[20];
            float sv = 0.f, qv = 0.f;
#pragma unroll
            for (int pp = 0; pp < NPOS; ++pp) {
                float hh = cj;
#pragma unroll
                for (int d = 0; d < DD; ++d)
                    hh = fmaf(kk[pp][d], wr[d], hh);
                sv += hh;
                qv = fmaf(hh, hh, qv);
            }
            s[j] += sv;
            q[j] += qv;
        }
    }
    // wave reduction of 64 values; lane v ends up holding value v
    float redv = 0.f;
#pragma unroll
    for (int v = 0; v < 2 * C0; ++v) {
        float val = (v < C0) ? s[v] : q[v - C0];
#pragma unroll
        for (int o = 32; o >= 1; o >>= 1) val += __shfl_xor(val, o);
        if (lane == v) redv = val;
    }
    atomicAdd(&sums[WS_P1 + (blockIdx.x & (NSLOT - 1)) * (2 * C0) + lane],
              redv);
}

// ---------------- finalize: slot-sum -> mean/var -> scale/shift --------
__global__ void finalize_kernel(float* __restrict__ ws, int nch, int srcOff,
                                int scOff, int shOff) {
    int j = threadIdx.x;
    if (j < nch) {
        float s = 0.f, q = 0.f;
#pragma unroll
        for (int k = 0; k < NSLOT; ++k) {
            s += ws[srcOff + k * 2 * nch + j];
            q += ws[srcOff + k * 2 * nch + nch + j];
        }
        const float invN = 1.0f / (float)(BB * TT);
        float mean = s * invN;
        float var = q * invN - mean * mean;
        float scv = rsqrtf(var + 1e-9f);
        ws[scOff + j] = scv;
        ws[shOff + j] = -mean * scv;
    }
}

// Load NPOS key rows and PIN them (defeat rematerialization — R5 bug).
#define LOAD_AND_PIN_KEYS()                                                  \
    const float* kbase = keys + ((size_t)b * TT + chunk * POSB) * DD;        \
    float kk[NPOS][DD];                                                      \
    _Pragma("unroll") for (int pp = 0; pp < NPOS; ++pp)                      \
        load_krow(kbase + (size_t)(tid + pp * NTH) * DD, kk[pp]);            \
    _Pragma("unroll") for (int pp = 0; pp < NPOS; ++pp)                      \
        _Pragma("unroll") for (int d = 0; d < DD; ++d) PIN(kk[pp][d]);

// j-loop over 32 layer-1 channels. All weight reads are wave-uniform
// (scalar path, zero LDS). h1[pp][c] accumulates layer-2 pre-acts (sans b1).
#define TOWER_JLOOP()                                                        \
    _Pragma("unroll 1") for (int j = 0; j < C0; ++j) {                       \
        const float* wr = bA + j * BLOB_J;                                   \
        const float* ur = W1 + j * C1;                                       \
        const float cj = wr[20];                                             \
        const float sc = stats[WS_SCALE0 + j];                               \
        const float sh = stats[WS_SHIFT0 + j];                               \
        const float al = a0[j];                                              \
        const float nal = 1.0f - al;                                         \
        float h[NPOS];                                                       \
        _Pragma("unroll") for (int pp = 0; pp < NPOS; ++pp) {                \
            float hh = cj;                                                   \
            _Pragma("unroll") for (int d = 0; d < DD; ++d)                   \
                hh = fmaf(kk[pp][d], wr[d], hh);                             \
            h[pp] = hh;                                                      \
        }                                                                    \
        _Pragma("unroll") for (int pp = 0; pp < NPOS; ++pp) {                \
            float pr = fast_sigmoid(fmaf(h[pp], sc, sh));                    \
            float h0d = h[pp] * fmaf(pr, nal, al);                           \
            _Pragma("unroll") for (int c = 0; c < C1; ++c)                   \
                h1[pp][c] = fmaf(h0d, ur[c], h1[pp][c]);                     \
        }                                                                    \
    }

// ---------------- pass 2: layer-2 pre-activation stats ----------------
__global__ __launch_bounds__(NTH, 2) void pass2_kernel(
    const float* __restrict__ keys, const float* __restrict__ blob,
    const float* __restrict__ a0, const float* __restrict__ W1,
    const float* __restrict__ b1, const float* __restrict__ stats,
    float* __restrict__ sums) {
    const int b = blockIdx.x >> 1, chunk = blockIdx.x & 1;
    const int tid = threadIdx.x, lane = tid & 63;
    const float* bA = blob + (size_t)b * BLOB_B;

    LOAD_AND_PIN_KEYS()

    float h1[NPOS][C1];
#pragma unroll
    for (int pp = 0; pp < NPOS; ++pp)
#pragma unroll
        for (int c = 0; c < C1; ++c) h1[pp][c] = 0.f;

    TOWER_JLOOP()

    // add b1 (uniform), accumulate thread-local stats
    float s1[C1], q1[C1];
#pragma unroll
    for (int c = 0; c < C1; ++c) {
        float bc = b1[c], sv = 0.f, qv = 0.f;
#pragma unroll
        for (int pp = 0; pp < NPOS; ++pp) {
            float v = h1[pp][c] + bc;
            sv += v;
            qv = fmaf(v, v, qv);
        }
        s1[c] = sv;
        q1[c] = qv;
    }
    float redv = 0.f;
#pragma unroll
    for (int v = 0; v < 2 * C1; ++v) {
        float val = (v < C1) ? s1[v] : q1[v - C1];
#pragma unroll
        for (int o = 32; o >= 1; o >>= 1) val += __shfl_xor(val, o);
        if (lane == v) redv = val;
    }
    if (lane < 2 * C1)
        atomicAdd(&sums[WS_P2 + (blockIdx.x & (NSLOT - 1)) * (2 * C1) + lane],
                  redv);
}

// ---------------- pass 3: full tower + weighted key-sum ----------------
__global__ __launch_bounds__(NTH, 2) void pass3_kernel(
    const float* __restrict__ keys, const float* __restrict__ blob,
    const float* __restrict__ a0, const float* __restrict__ W1,
    const float* __restrict__ b1, const float* __restrict__ a1,
    const float* __restrict__ wk, const float* __restrict__ bk,
    const float* __restrict__ stats, float* __restrict__ out) {
    const int b = blockIdx.x >> 1, chunk = blockIdx.x & 1;
    const int tid = threadIdx.x, lane = tid & 63;
    const float* bA = blob + (size_t)b * BLOB_B;

    LOAD_AND_PIN_KEYS()

    float h1[NPOS][C1];
#pragma unroll
    for (int pp = 0; pp < NPOS; ++pp)
#pragma unroll
        for (int c = 0; c < C1; ++c) h1[pp][c] = 0.f;

    TOWER_JLOOP()

    // dice1 + score + weighted-key accumulation (all uniform reads scalar)
    const float bkv = bk[0];
    float oacc[DD];
#pragma unroll
    for (int d = 0; d < DD; ++d) oacc[d] = 0.f;
#pragma unroll
    for (int pp = 0; pp < NPOS; ++pp) {
        float score = bkv;
#pragma unroll
        for (int c = 0; c < C1; ++c) {
            float v = h1[pp][c] + b1[c];
            float pr = fast_sigmoid(
                fmaf(v, stats[WS_SCALE1 + c], stats[WS_SHIFT1 + c]));
            float al = a1[c];
            float hd = v * fmaf(pr, 1.0f - al, al);
            score = fmaf(hd, wk[c], score);
        }
#pragma unroll
        for (int d = 0; d < DD; ++d)
            oacc[d] = fmaf(score, kk[pp][d], oacc[d]);
    }
    float redv = 0.f;
#pragma unroll
    for (int v = 0; v < DD; ++v) {
        float val = oacc[v];
#pragma unroll
        for (int o = 32; o >= 1; o >>= 1) val += __shfl_xor(val, o);
        if (lane == v) redv = val;
    }
    if (lane < DD) atomicAdd(&out[b * DD + lane], redv);
}

extern "C" void kernel_launch(void* const* d_in, const int* in_sizes, int n_in,
                              void* d_out, int out_size, void* d_ws,
                              size_t ws_size, hipStream_t stream) {
    const float* keys = (const float*)d_in[0];
    const float* query = (const float*)d_in[1];
    // d_in[2] = mask: intentionally unused
    const float* W0 = (const float*)d_in[3];
    const float* b0 = (const float*)d_in[4];
    const float* a0 = (const float*)d_in[5];
    const float* W1 = (const float*)d_in[6];
    const float* b1 = (const float*)d_in[7];
    const float* a1 = (const float*)d_in[8];
    const float* wk = (const float*)d_in[9];
    const float* bk = (const float*)d_in[10];
    float* out = (float*)d_out;
    float* ws = (float*)d_ws;
    float* blob = ws + WS_BLOB;  // 512*768 floats = 1.5 MB scratch

    hipMemsetAsync(ws, 0, WS_ZERO_N * sizeof(float), stream);
    hipMemsetAsync(out, 0, (size_t)out_size * sizeof(float), stream);

    prep_kernel<<<BB / 2, 64, 0, stream>>>(query, W0, b0, blob);

    pass1_kernel<<<BB, NTH, 0, stream>>>(keys, blob, ws);
    finalize_kernel<<<1, 32, 0, stream>>>(ws, C0, WS_P1, WS_SCALE0, WS_SHIFT0);
    pass2_kernel<<<BB * 2, NTH, 0, stream>>>(keys, blob, a0, W1, b1, ws, ws);
    finalize_kernel<<<1, 16, 0, stream>>>(ws, C1, WS_P2, WS_SCALE1, WS_SHIFT1);
    pass3_kernel<<<BB * 2, NTH, 0, stream>>>(keys, blob, a0, W1, b1, a1, wk,
                                             bk, ws, out);
}

// Round 3
// 273.970 us; speedup vs baseline: 1.0607x; 1.0216x over previous
//
#include <hip/hip_runtime.h>
#include <hip/hip_cooperative_groups.h>

namespace cg = cooperative_groups;

// DIN attention unit, MI355X — round 9: cooperative fusion, hardened.
// R8 failed (absmax ~= |ref|max): either unchecked cooperative-launch
// failure, or stale per-XCD L2 readback of ws sums after grid.sync()
// (atomicAdd lands at the coherent point; plain loads can hit a stale
// zero line -> rsqrt(1e-9) -> saturated garbage). Fixes:
//  (a) ALL cross-block ws readbacks via __hip_atomic_load(AGENT scope).
//  (b) cooperative path gated by a one-time occupancy query + checked
//      return code; guaranteed-correct 5-dispatch split path as fallback.
//  (c) identical phase bodies shared by both paths.
// Weights stay on the scalar path (R7 win). One block per batch -> out is
// a plain store. mask input UNUSED (reference bug reproduced).

#define BB 512
#define TT 2048
#define DD 20
#define C0 32
#define C1 16

#define NTH 256             // 4 waves/block
#define NPOS 4              // positions per register round
#define POSB (NTH * NPOS)   // 1024 positions per round
#define NROUND (TT / POSB)  // 2 rounds per batch
#define NSLOT 8             // atomic slot-split

// ws float offsets
#define WS_P1 0              // 8 slots * (32 sum + 32 sq)
#define WS_P2 512            // 8 slots * (16 sum + 16 sq)
#define WS_ZERO_N 768        // floats to zero each launch
#define WS_BLOB 896
#define BLOB_J 24            // 20 wM + c + pad
#define BLOB_B (C0 * BLOB_J) // 768 floats per batch

#define PIN(x) asm volatile("" : "+v"(x))
#define AGLOAD(p) \
    __hip_atomic_load((p), __ATOMIC_RELAXED, __HIP_MEMORY_SCOPE_AGENT)

__device__ __forceinline__ float fast_sigmoid(float x) {
    return __builtin_amdgcn_rcpf(1.0f + __expf(-x));
}

__device__ __forceinline__ void load_krow(const float* __restrict__ row,
                                          float* kk) {
    const float4* kr = (const float4*)row;  // rows are 80B => 16B aligned
    float4 a = kr[0], b = kr[1], c = kr[2], d = kr[3], e = kr[4];
    kk[0] = a.x; kk[1] = a.y; kk[2] = a.z; kk[3] = a.w;
    kk[4] = b.x; kk[5] = b.y; kk[6] = b.z; kk[7] = b.w;
    kk[8] = c.x; kk[9] = c.y; kk[10] = c.z; kk[11] = c.w;
    kk[12] = d.x; kk[13] = d.y; kk[14] = d.z; kk[15] = d.w;
    kk[16] = e.x; kk[17] = e.y; kk[18] = e.z; kk[19] = e.w;
}

// ---------------- prep: fold query into layer-1 weights ----------------
__global__ void prep_kernel(const float* __restrict__ query,
                            const float* __restrict__ W0,
                            const float* __restrict__ b0,
                            float* __restrict__ blob) {
    const int b = blockIdx.x * 2 + (threadIdx.x >> 5);
    const int j = threadIdx.x & 31;
    float cj = b0[j];
    float* dst = blob + (size_t)b * BLOB_B + j * BLOB_J;
#pragma unroll
    for (int d = 0; d < DD; ++d) {
        float w_q = W0[d * C0 + j];
        float w_k = W0[(DD + d) * C0 + j];
        float w_d = W0[(2 * DD + d) * C0 + j];
        float w_p = W0[(3 * DD + d) * C0 + j];
        float qd = query[b * DD + d];
        dst[d] = w_k - w_d + qd * w_p;
        cj = fmaf(qd, w_q + w_d, cj);
    }
    dst[20] = cj;
}

// Load NPOS key rows for round r and PIN them (defeat rematerialization).
#define LOAD_AND_PIN_KEYS(r)                                                 \
    float kk[NPOS][DD];                                                      \
    _Pragma("unroll") for (int pp = 0; pp < NPOS; ++pp)                      \
        load_krow(kbase + (size_t)((r)*POSB + tid + pp * NTH) * DD, kk[pp]); \
    _Pragma("unroll") for (int pp = 0; pp < NPOS; ++pp)                      \
        _Pragma("unroll") for (int d = 0; d < DD; ++d) PIN(kk[pp][d]);

// j-loop over 32 layer-1 channels. Weights on scalar path; scale/shift
// from LDS (uniform broadcast ds_read_b64).
#define TOWER_JLOOP()                                                        \
    _Pragma("unroll 1") for (int j = 0; j < C0; ++j) {                       \
        const float* wr = bA + j * BLOB_J;                                   \
        const float* ur = W1 + j * C1;                                       \
        const float cj = wr[20];                                             \
        const float2 ss = lss0[j];                                           \
        const float al = a0[j];                                              \
        const float nal = 1.0f - al;                                         \
        float h[NPOS];                                                       \
        _Pragma("unroll") for (int pp = 0; pp < NPOS; ++pp) {                \
            float hh = cj;                                                   \
            _Pragma("unroll") for (int d = 0; d < DD; ++d)                   \
                hh = fmaf(kk[pp][d], wr[d], hh);                             \
            h[pp] = hh;                                                      \
        }                                                                    \
        _Pragma("unroll") for (int pp = 0; pp < NPOS; ++pp) {                \
            float pr = fast_sigmoid(fmaf(h[pp], ss.x, ss.y));                \
            float h0d = h[pp] * fmaf(pr, nal, al);                           \
            _Pragma("unroll") for (int c = 0; c < C1; ++c)                   \
                h1[pp][c] = fmaf(h0d, ur[c], h1[pp][c]);                     \
        }                                                                    \
    }

// ================= shared phase bodies =================
__device__ __forceinline__ void phase1_body(int b, int tid, int lane,
                                            const float* __restrict__ bA,
                                            const float* __restrict__ kbase,
                                            float* __restrict__ ws) {
    float s[C0], q[C0];
#pragma unroll
    for (int j = 0; j < C0; ++j) { s[j] = 0.f; q[j] = 0.f; }
#pragma unroll 1
    for (int r = 0; r < NROUND; ++r) {
        LOAD_AND_PIN_KEYS(r)
#pragma unroll
        for (int j = 0; j < C0; ++j) {
            const float* wr = bA + j * BLOB_J;  // uniform -> s_load
            const float cj = wr[20];
            float sv = 0.f, qv = 0.f;
#pragma unroll
            for (int pp = 0; pp < NPOS; ++pp) {
                float hh = cj;
#pragma unroll
                for (int d = 0; d < DD; ++d) hh = fmaf(kk[pp][d], wr[d], hh);
                sv += hh;
                qv = fmaf(hh, hh, qv);
            }
            s[j] += sv;
            q[j] += qv;
        }
    }
    float redv = 0.f;
#pragma unroll
    for (int v = 0; v < 2 * C0; ++v) {
        float val = (v < C0) ? s[v] : q[v - C0];
#pragma unroll
        for (int o = 32; o >= 1; o >>= 1) val += __shfl_xor(val, o);
        if (lane == v) redv = val;
    }
    atomicAdd(&ws[WS_P1 + (b & (NSLOT - 1)) * (2 * C0) + lane], redv);
}

__device__ __forceinline__ void finalize0(int tid, float* __restrict__ ws,
                                          float2* __restrict__ lss0) {
    if (tid < C0) {
        float sv = 0.f, qv = 0.f;
#pragma unroll
        for (int k = 0; k < NSLOT; ++k) {
            sv += AGLOAD(&ws[WS_P1 + k * (2 * C0) + tid]);
            qv += AGLOAD(&ws[WS_P1 + k * (2 * C0) + C0 + tid]);
        }
        const float invN = 1.0f / (float)(BB * TT);
        float mean = sv * invN;
        float var = qv * invN - mean * mean;
        float sc = rsqrtf(var + 1e-9f);
        lss0[tid] = make_float2(sc, -mean * sc);
    }
}

__device__ __forceinline__ void phase2_body(
    int b, int tid, int lane, const float* __restrict__ bA,
    const float* __restrict__ kbase, const float* __restrict__ a0,
    const float* __restrict__ W1, const float* __restrict__ b1,
    const float2* __restrict__ lss0, float* __restrict__ ws) {
    float s1[C1], q1[C1];
#pragma unroll
    for (int c = 0; c < C1; ++c) { s1[c] = 0.f; q1[c] = 0.f; }
#pragma unroll 1
    for (int r = 0; r < NROUND; ++r) {
        LOAD_AND_PIN_KEYS(r)
        float h1[NPOS][C1];
#pragma unroll
        for (int pp = 0; pp < NPOS; ++pp)
#pragma unroll
            for (int c = 0; c < C1; ++c) h1[pp][c] = 0.f;
        TOWER_JLOOP()
#pragma unroll
        for (int c = 0; c < C1; ++c) {
            float bc = b1[c];
#pragma unroll
            for (int pp = 0; pp < NPOS; ++pp) {
                float v = h1[pp][c] + bc;
                s1[c] += v;
                q1[c] = fmaf(v, v, q1[c]);
            }
        }
    }
    float redv = 0.f;
#pragma unroll
    for (int v = 0; v < 2 * C1; ++v) {
        float val = (v < C1) ? s1[v] : q1[v - C1];
#pragma unroll
        for (int o = 32; o >= 1; o >>= 1) val += __shfl_xor(val, o);
        if (lane == v) redv = val;
    }
    if (lane < 2 * C1)
        atomicAdd(&ws[WS_P2 + (b & (NSLOT - 1)) * (2 * C1) + lane], redv);
}

__device__ __forceinline__ void finalize1(int tid, float* __restrict__ ws,
                                          const float* __restrict__ a1,
                                          const float* __restrict__ wk,
                                          float4* __restrict__ ld1v) {
    if (tid < C1) {
        float sv = 0.f, qv = 0.f;
#pragma unroll
        for (int k = 0; k < NSLOT; ++k) {
            sv += AGLOAD(&ws[WS_P2 + k * (2 * C1) + tid]);
            qv += AGLOAD(&ws[WS_P2 + k * (2 * C1) + C1 + tid]);
        }
        const float invN = 1.0f / (float)(BB * TT);
        float mean = sv * invN;
        float var = qv * invN - mean * mean;
        float sc = rsqrtf(var + 1e-9f);
        ld1v[tid] = make_float4(sc, -mean * sc, a1[tid], wk[tid]);
    }
}

__device__ __forceinline__ void phase3_body(
    int b, int tid, int lane, int wave, const float* __restrict__ bA,
    const float* __restrict__ kbase, const float* __restrict__ a0,
    const float* __restrict__ W1, const float* __restrict__ b1,
    const float* __restrict__ bk, const float2* __restrict__ lss0,
    const float4* __restrict__ ld1v, float (*red)[DD],
    float* __restrict__ out) {
    const float bkv = bk[0];
    float oacc[DD];
#pragma unroll
    for (int d = 0; d < DD; ++d) oacc[d] = 0.f;
#pragma unroll 1
    for (int r = 0; r < NROUND; ++r) {
        LOAD_AND_PIN_KEYS(r)
        float h1[NPOS][C1];
#pragma unroll
        for (int pp = 0; pp < NPOS; ++pp)
#pragma unroll
            for (int c = 0; c < C1; ++c) h1[pp][c] = 0.f;
        TOWER_JLOOP()
#pragma unroll
        for (int pp = 0; pp < NPOS; ++pp) {
            float score = bkv;
#pragma unroll
            for (int c = 0; c < C1; ++c) {
                float v = h1[pp][c] + b1[c];
                float4 dv = ld1v[c];
                float pr = fast_sigmoid(fmaf(v, dv.x, dv.y));
                float hd = v * fmaf(pr, 1.0f - dv.z, dv.z);
                score = fmaf(hd, dv.w, score);
            }
#pragma unroll
            for (int d = 0; d < DD; ++d)
                oacc[d] = fmaf(score, kk[pp][d], oacc[d]);
        }
    }
    float redv = 0.f;
#pragma unroll
    for (int v = 0; v < DD; ++v) {
        float val = oacc[v];
#pragma unroll
        for (int o = 32; o >= 1; o >>= 1) val += __shfl_xor(val, o);
        if (lane == v) redv = val;
    }
    if (lane < DD) red[wave][lane] = redv;
    __syncthreads();
    if (tid < DD)
        out[b * DD + tid] =
            red[0][tid] + red[1][tid] + red[2][tid] + red[3][tid];
}

// ---------------- fused persistent kernel: all 3 passes ----------------
__global__ __launch_bounds__(NTH, 2) void fused_kernel(
    const float* __restrict__ keys, const float* __restrict__ blob,
    const float* __restrict__ a0, const float* __restrict__ W1,
    const float* __restrict__ b1, const float* __restrict__ a1,
    const float* __restrict__ wk, const float* __restrict__ bk,
    float* __restrict__ ws, float* __restrict__ out) {
    const int b = blockIdx.x;  // one batch per block
    const int tid = threadIdx.x, wave = tid >> 6, lane = tid & 63;
    const float* bA = blob + (size_t)b * BLOB_B;
    const float* kbase = keys + (size_t)b * TT * DD;

    __shared__ float2 lss0[C0];
    __shared__ float4 ld1v[C1];
    __shared__ float red[4][DD];

    phase1_body(b, tid, lane, bA, kbase, ws);
    cg::this_grid().sync();
    finalize0(tid, ws, lss0);
    __syncthreads();
    phase2_body(b, tid, lane, bA, kbase, a0, W1, b1, lss0, ws);
    cg::this_grid().sync();
    finalize1(tid, ws, a1, wk, ld1v);
    __syncthreads();
    phase3_body(b, tid, lane, wave, bA, kbase, a0, W1, b1, bk, lss0, ld1v,
                red, out);
}

// ---------------- split fallback kernels ----------------
__global__ __launch_bounds__(NTH, 2) void pass1_kernel(
    const float* __restrict__ keys, const float* __restrict__ blob,
    float* __restrict__ ws) {
    const int b = blockIdx.x;
    const int tid = threadIdx.x, lane = tid & 63;
    phase1_body(b, tid, lane, blob + (size_t)b * BLOB_B,
                keys + (size_t)b * TT * DD, ws);
}

__global__ __launch_bounds__(NTH, 2) void pass2_kernel(
    const float* __restrict__ keys, const float* __restrict__ blob,
    const float* __restrict__ a0, const float* __restrict__ W1,
    const float* __restrict__ b1, float* __restrict__ ws) {
    const int b = blockIdx.x;
    const int tid = threadIdx.x, lane = tid & 63;
    __shared__ float2 lss0[C0];
    finalize0(tid, ws, lss0);
    __syncthreads();
    phase2_body(b, tid, lane, blob + (size_t)b * BLOB_B,
                keys + (size_t)b * TT * DD, a0, W1, b1, lss0, ws);
}

__global__ __launch_bounds__(NTH, 2) void pass3_kernel(
    const float* __restrict__ keys, const float* __restrict__ blob,
    const float* __restrict__ a0, const float* __restrict__ W1,
    const float* __restrict__ b1, const float* __restrict__ a1,
    const float* __restrict__ wk, const float* __restrict__ bk,
    float* __restrict__ ws, float* __restrict__ out) {
    const int b = blockIdx.x;
    const int tid = threadIdx.x, wave = tid >> 6, lane = tid & 63;
    __shared__ float2 lss0[C0];
    __shared__ float4 ld1v[C1];
    __shared__ float red[4][DD];
    finalize0(tid, ws, lss0);
    finalize1(tid, ws, a1, wk, ld1v);
    __syncthreads();
    phase3_body(b, tid, lane, wave, blob + (size_t)b * BLOB_B,
                keys + (size_t)b * TT * DD, a0, W1, b1, bk, lss0, ld1v, red,
                out);
}

extern "C" void kernel_launch(void* const* d_in, const int* in_sizes, int n_in,
                              void* d_out, int out_size, void* d_ws,
                              size_t ws_size, hipStream_t stream) {
    const float* keys = (const float*)d_in[0];
    const float* query = (const float*)d_in[1];
    // d_in[2] = mask: intentionally unused
    const float* W0 = (const float*)d_in[3];
    const float* b0 = (const float*)d_in[4];
    const float* a0 = (const float*)d_in[5];
    const float* W1 = (const float*)d_in[6];
    const float* b1 = (const float*)d_in[7];
    const float* a1 = (const float*)d_in[8];
    const float* wk = (const float*)d_in[9];
    const float* bk = (const float*)d_in[10];
    float* out = (float*)d_out;
    float* ws = (float*)d_ws;
    float* blob = ws + WS_BLOB;  // 512*768 floats = 1.5 MB scratch
    const float* blobc = blob;

    hipMemsetAsync(ws, 0, WS_ZERO_N * sizeof(float), stream);
    prep_kernel<<<BB / 2, 64, 0, stream>>>(query, W0, b0, blob);

    // One-time host-side decision: is the 512-block cooperative grid
    // guaranteed co-resident? (Queries are capture-safe; result cached.)
    static int use_coop = -1;
    if (use_coop < 0) {
        int nb = 0, ncu = 0;
        hipError_t e1 = hipOccupancyMaxActiveBlocksPerMultiprocessor(
            &nb, (const void*)fused_kernel, NTH, 0);
        hipDeviceProp_t prop;
        hipError_t e2 = hipGetDeviceProperties(&prop, 0);
        if (e2 == hipSuccess) ncu = prop.multiProcessorCount;
        use_coop = (e1 == hipSuccess && e2 == hipSuccess && nb * ncu >= BB)
                       ? 1
                       : 0;
    }

    if (use_coop) {
        void* args[] = {(void*)&keys, (void*)&blobc, (void*)&a0, (void*)&W1,
                        (void*)&b1,   (void*)&a1,    (void*)&wk, (void*)&bk,
                        (void*)&ws,   (void*)&out};
        hipError_t e = hipLaunchCooperativeKernel(
            (const void*)fused_kernel, dim3(BB), dim3(NTH), args, 0, stream);
        if (e != hipSuccess) use_coop = 0;  // record failed -> use split path
    }
    if (!use_coop) {
        pass1_kernel<<<BB, NTH, 0, stream>>>(keys, blob, ws);
        pass2_kernel<<<BB, NTH, 0, stream>>>(keys, blob, a0, W1, b1, ws);
        pass3_kernel<<<BB, NTH, 0, stream>>>(keys, blob, a0, W1, b1, a1, wk,
                                             bk, ws, out);
    }
}